// Round 20
// baseline (1358.474 us; speedup 1.0000x reference)
//
#include <hip/hip_runtime.h>
#include <hip/hip_fp16.h>

#define N_NODES 100000
#define N_EDGES 1600000
#define C_IN 128
#define C_H 64
#define C_OUT 40

// --- bucketed counting sort params ---
#define BK_SHIFT 9
#define BK_NODES 512
#define NBKT ((N_NODES + BK_NODES - 1) / BK_NODES)   // 196
#define NSH 8
#define CAPS 1536
#define TILE_E 8192
#define NTILE ((N_EDGES + TILE_E - 1) / TILE_E)       // 196
#define EPT 32

#define H_PAD 68
#define W2_PAD 84
#define XH_PAD 136

typedef __attribute__((ext_vector_type(8))) _Float16 f16x8;
typedef __attribute__((ext_vector_type(4))) _Float16 f16x4;
typedef __attribute__((ext_vector_type(4))) float f32x4;

// ---------------------------------------------------------------------------
// K0: block-local binning, then dense run reservation + contiguous writes
// ---------------------------------------------------------------------------
__global__ __launch_bounds__(256) void k_bscat(const int* __restrict__ ei,
                                               int* __restrict__ bcnt,
                                               long long* __restrict__ bk) {
    __shared__ int lcnt[NBKT], lbase[NBKT];
    const int t = threadIdx.x;
    const long e0 = (long)blockIdx.x * TILE_E;
    const int nE = (int)min((long)TILE_E, (long)N_EDGES - e0);
    for (int i = t; i < NBKT; i += 256) lcnt[i] = 0;
    __syncthreads();
    for (int j = 0; j < EPT; ++j) {
        int idx = t + j * 256;
        if (idx < nE) atomicAdd(&lcnt[ei[N_EDGES + e0 + idx] >> BK_SHIFT], 1);
    }
    __syncthreads();
    const int sh = blockIdx.x & (NSH - 1);
    for (int i = t; i < NBKT; i += 256)
        lbase[i] = lcnt[i] ? atomicAdd(&bcnt[i * NSH + sh], lcnt[i]) : 0;
    __syncthreads();
    for (int i = t; i < NBKT; i += 256) lcnt[i] = 0;
    __syncthreads();
    for (int j = 0; j < EPT; ++j) {
        int idx = t + j * 256;
        if (idx < nE) {
            int s = ei[e0 + idx], d = ei[N_EDGES + e0 + idx];
            int b = d >> BK_SHIFT;
            int pos = lbase[b] + atomicAdd(&lcnt[b], 1);
            if (pos < CAPS)
                bk[((long)b * NSH + sh) * CAPS + pos] =
                    ((long long)(d & (BK_NODES - 1)) << 32) | (unsigned)s;
        }
    }
}

__global__ __launch_bounds__(256) void k_scan_bases(const int* __restrict__ bcnt,
                                                    int* __restrict__ bbase,
                                                    int* __restrict__ row_ptr) {
    __shared__ int ls[256];
    int t = threadIdx.x;
    int tot = 0;
    if (t < NBKT)
        for (int j = 0; j < NSH; ++j) tot += min(bcnt[t * NSH + j], CAPS);
    ls[t] = tot;
    __syncthreads();
    for (int off = 1; off < 256; off <<= 1) {
        int u = (t >= off) ? ls[t - off] : 0;
        __syncthreads();
        ls[t] += u;
        __syncthreads();
    }
    if (t < NBKT) bbase[t] = ls[t] - tot;
    if (t == NBKT - 1) row_ptr[N_NODES] = ls[t];
}

__global__ __launch_bounds__(256) void k_csr(const long long* __restrict__ bk,
                                             const int* __restrict__ bcnt,
                                             const int* __restrict__ bbase,
                                             int* __restrict__ row_ptr,
                                             int* __restrict__ csr) {
    __shared__ int deg[BK_NODES], exc[BK_NODES], ctr[BK_NODES];
    __shared__ int ls[256];
    __shared__ int shn[NSH];
    const int b = blockIdx.x, t = threadIdx.x;
    if (t < NSH) shn[t] = min(bcnt[b * NSH + t], CAPS);
    for (int i = t; i < BK_NODES; i += 256) { deg[i] = 0; ctr[i] = 0; }
    __syncthreads();
    for (int j = 0; j < NSH; ++j) {
        const long long* src = bk + ((long)b * NSH + j) * CAPS;
        const int n = shn[j];
        for (int i = t; i < n; i += 256)
            atomicAdd(&deg[(int)(src[i] >> 32)], 1);
    }
    __syncthreads();
    int s0 = deg[2 * t], s1 = deg[2 * t + 1];
    ls[t] = s0 + s1;
    __syncthreads();
    for (int off = 1; off < 256; off <<= 1) {
        int u = (t >= off) ? ls[t - off] : 0;
        __syncthreads();
        ls[t] += u;
        __syncthreads();
    }
    const int tb = ls[t] - (s0 + s1);
    exc[2 * t] = tb;
    exc[2 * t + 1] = tb + s0;
    const int node0 = b * BK_NODES;
    const int gbase = bbase[b];
    if (node0 + 2 * t < N_NODES) row_ptr[node0 + 2 * t] = gbase + tb;
    if (node0 + 2 * t + 1 < N_NODES) row_ptr[node0 + 2 * t + 1] = gbase + tb + s0;
    __syncthreads();
    for (int j = 0; j < NSH; ++j) {
        const long long* src = bk + ((long)b * NSH + j) * CAPS;
        const int n = shn[j];
        for (int i = t; i < n; i += 256) {
            long long v = src[i];
            int dl = (int)(v >> 32);
            int pos = gbase + exc[dl] + atomicAdd(&ctr[dl], 1);
            csr[pos] = (int)(v & 0xffffffffLL);
        }
    }
}

// ---------------------------------------------------------------------------
// K1 (MFMA): y1 = x@Wl1^T (-> fp16)  AND  z1 = x@Wr1^T (-> fp16)
// ---------------------------------------------------------------------------
__global__ __launch_bounds__(256) void k_gemm12(const float* __restrict__ x,
                                                const float* __restrict__ Wl1,
                                                const float* __restrict__ Wr1,
                                                __half* __restrict__ y1h,
                                                __half* __restrict__ z1h) {
    __shared__ _Float16 xs_h[64 * XH_PAD];
    __shared__ _Float16 wl_h[64 * XH_PAD];
    __shared__ _Float16 wr_h[64 * XH_PAD];
    const int tid = threadIdx.x;
    const int r0 = blockIdx.x * 64;
#pragma unroll
    for (int it = 0; it < 8; ++it) {
        int idx = tid * 4 + it * 1024;
        int row = idx >> 7, k = idx & 127;
        int gr = min(r0 + row, N_NODES - 1);
        float4 v = *(const float4*)(x + (long)gr * C_IN + k);
        f16x4 h = {(_Float16)v.x, (_Float16)v.y, (_Float16)v.z, (_Float16)v.w};
        *(f16x4*)(xs_h + row * XH_PAD + k) = h;
    }
#pragma unroll
    for (int it = 0; it < 8; ++it) {
        int idx = tid * 4 + it * 1024;
        int c = idx >> 7, k = idx & 127;
        float4 vl = *(const float4*)(Wl1 + (long)c * C_IN + k);
        float4 vr = *(const float4*)(Wr1 + (long)c * C_IN + k);
        f16x4 hl = {(_Float16)vl.x, (_Float16)vl.y, (_Float16)vl.z, (_Float16)vl.w};
        f16x4 hr = {(_Float16)vr.x, (_Float16)vr.y, (_Float16)vr.z, (_Float16)vr.w};
        *(f16x4*)(wl_h + c * XH_PAD + k) = hl;
        *(f16x4*)(wr_h + c * XH_PAD + k) = hr;
    }
    __syncthreads();
    const int w = tid >> 6, l = tid & 63;
    const int lr = l & 15, kg = l >> 4;
    f16x8 af[4];
#pragma unroll
    for (int kk = 0; kk < 4; ++kk)
        af[kk] = *(const f16x8*)(xs_h + (w * 16 + lr) * XH_PAD + kk * 32 + kg * 8);
    f32x4 acc[8] = {};
#pragma unroll
    for (int t = 0; t < 4; ++t) {
#pragma unroll
        for (int kk = 0; kk < 4; ++kk) {
            f16x8 bl = *(const f16x8*)(wl_h + (t * 16 + lr) * XH_PAD + kk * 32 + kg * 8);
            acc[t] = __builtin_amdgcn_mfma_f32_16x16x32_f16(af[kk], bl, acc[t], 0, 0, 0);
            f16x8 br = *(const f16x8*)(wr_h + (t * 16 + lr) * XH_PAD + kk * 32 + kg * 8);
            acc[4 + t] = __builtin_amdgcn_mfma_f32_16x16x32_f16(af[kk], br, acc[4 + t], 0, 0, 0);
        }
    }
    const int rbase = r0 + w * 16 + kg * 4;
#pragma unroll
    for (int t = 0; t < 4; ++t) {
#pragma unroll
        for (int j = 0; j < 4; ++j) {
            int row = rbase + j;
            if (row < N_NODES) {
                y1h[((long)row << 6) + t * 16 + lr] = __float2half_rn(acc[t][j]);
                z1h[((long)row << 6) + t * 16 + lr] = __float2half_rn(acc[4 + t][j]);
            }
        }
    }
}

// ---------------------------------------------------------------------------
// K2 (FUSED): gather-mean of y1 -> h = relu(mean + bl1 + z1) in LDS ->
//             [y2|z2] = h @ [Wl2^T|Wr2^T]   (mean never touches HBM)
// 1024 threads, 64 nodes/block; wave w gathers nodes w*4..w*4+3 sequentially
// (gather inner loop identical to proven k_gather1). Phase 2: thread =
// (row=tid>>4, 5 cols). LDS 38.9 KB -> 2 blocks/CU (32 waves/CU).
// ---------------------------------------------------------------------------
__global__ __launch_bounds__(1024) void k_gl2(
    const int* __restrict__ row_ptr, const int* __restrict__ csr,
    const __half* __restrict__ y1h, const __half* __restrict__ z1h,
    const float* __restrict__ bl1, const float* __restrict__ Wl2,
    const float* __restrict__ Wr2, __half* __restrict__ y2h,
    __half* __restrict__ z2h) {
    __shared__ float hs[64 * H_PAD];      // 17.4 KB
    __shared__ float W2s[C_H * W2_PAD];   // 21.5 KB
    const int tid = threadIdx.x;
    const int r0 = blockIdx.x * 64;
    for (int i = tid; i < C_OUT * C_H; i += 1024) {
        int c = i >> 6, k = i & 63;
        W2s[k * W2_PAD + c] = Wl2[i];
        W2s[k * W2_PAD + 40 + c] = Wr2[i];
    }
    const int wave = tid >> 6, lane = tid & 63;
    const int g = lane >> 4, l = lane & 15;
    // ---- gather phase: 4 nodes per wave, sequential ----
    for (int t = 0; t < 4; ++t) {
        int rl = wave * 4 + t;
        int r = r0 + rl;
        if (r >= N_NODES) break;
        int b = row_ptr[r], e = row_ptr[r + 1];
        float4 acc = {0.f, 0.f, 0.f, 0.f};
        union { uint2 u; __half2 h[2]; } c;
        int i = b + g;
        for (; i + 12 < e; i += 16) {
            int sA = csr[i], sB = csr[i + 4], sC = csr[i + 8], sD = csr[i + 12];
            uint2 vA = *(const uint2*)(y1h + ((long)sA << 6) + (l << 2));
            uint2 vB = *(const uint2*)(y1h + ((long)sB << 6) + (l << 2));
            uint2 vC = *(const uint2*)(y1h + ((long)sC << 6) + (l << 2));
            uint2 vD = *(const uint2*)(y1h + ((long)sD << 6) + (l << 2));
            float2 f0, f1;
            c.u = vA; f0 = __half22float2(c.h[0]); f1 = __half22float2(c.h[1]);
            acc.x += f0.x; acc.y += f0.y; acc.z += f1.x; acc.w += f1.y;
            c.u = vB; f0 = __half22float2(c.h[0]); f1 = __half22float2(c.h[1]);
            acc.x += f0.x; acc.y += f0.y; acc.z += f1.x; acc.w += f1.y;
            c.u = vC; f0 = __half22float2(c.h[0]); f1 = __half22float2(c.h[1]);
            acc.x += f0.x; acc.y += f0.y; acc.z += f1.x; acc.w += f1.y;
            c.u = vD; f0 = __half22float2(c.h[0]); f1 = __half22float2(c.h[1]);
            acc.x += f0.x; acc.y += f0.y; acc.z += f1.x; acc.w += f1.y;
        }
        for (; i + 4 < e; i += 8) {
            int sA = csr[i], sB = csr[i + 4];
            uint2 vA = *(const uint2*)(y1h + ((long)sA << 6) + (l << 2));
            uint2 vB = *(const uint2*)(y1h + ((long)sB << 6) + (l << 2));
            float2 f0, f1;
            c.u = vA; f0 = __half22float2(c.h[0]); f1 = __half22float2(c.h[1]);
            acc.x += f0.x; acc.y += f0.y; acc.z += f1.x; acc.w += f1.y;
            c.u = vB; f0 = __half22float2(c.h[0]); f1 = __half22float2(c.h[1]);
            acc.x += f0.x; acc.y += f0.y; acc.z += f1.x; acc.w += f1.y;
        }
        if (i < e) {
            int s = csr[i];
            c.u = *(const uint2*)(y1h + ((long)s << 6) + (l << 2));
            float2 f0 = __half22float2(c.h[0]), f1 = __half22float2(c.h[1]);
            acc.x += f0.x; acc.y += f0.y; acc.z += f1.x; acc.w += f1.y;
        }
        for (int m = 16; m < 64; m <<= 1) {
            acc.x += __shfl_xor(acc.x, m);
            acc.y += __shfl_xor(acc.y, m);
            acc.z += __shfl_xor(acc.z, m);
            acc.w += __shfl_xor(acc.w, m);
        }
        if (g == 0) {
            float inv = 1.f / fmaxf((float)(e - b), 1.f);
            union { uint2 u; __half2 h[2]; } cz;
            cz.u = *(const uint2*)(z1h + ((long)r << 6) + (l << 2));
            float2 z0 = __half22float2(cz.h[0]), z1v = __half22float2(cz.h[1]);
            const float4 bb = *(const float4*)(bl1 + (l << 2));
            float4 h;
            h.x = fmaxf(acc.x * inv + bb.x + z0.x, 0.f);
            h.y = fmaxf(acc.y * inv + bb.y + z0.y, 0.f);
            h.z = fmaxf(acc.z * inv + bb.z + z1v.x, 0.f);
            h.w = fmaxf(acc.w * inv + bb.w + z1v.y, 0.f);
            *(float4*)(hs + rl * H_PAD + (l << 2)) = h;
        }
    }
    __syncthreads();
    // ---- phase 2: [y2|z2] = h @ [Wl2^T|Wr2^T]; 1 row x 5 cols per thread ----
    {
        const int row_l = tid >> 4, tj = tid & 15;
        float acc[5] = {};
        for (int k0 = 0; k0 < C_H; k0 += 4) {
            float4 hr = *(const float4*)(hs + row_l * H_PAD + k0);
            const float* hp = (const float*)&hr;
#pragma unroll
            for (int kk = 0; kk < 4; ++kk) {
                float hv = hp[kk];
#pragma unroll
                for (int cc = 0; cc < 5; ++cc)
                    acc[cc] = fmaf(hv, W2s[(k0 + kk) * W2_PAD + tj * 5 + cc], acc[cc]);
            }
        }
        int row = r0 + row_l;
        if (row < N_NODES) {
#pragma unroll
            for (int cc = 0; cc < 5; ++cc) {
                int cidx = tj * 5 + cc;
                if (cidx < C_OUT)
                    y2h[((long)row << 6) + cidx] = __float2half_rn(acc[cc]);
                else
                    z2h[((long)row << 6) + (cidx - C_OUT)] = __float2half_rn(acc[cc]);
            }
        }
    }
}

// ---------------------------------------------------------------------------
// K3: fused gather-mean of y2 + bias + z2 (fp16) + softmax -> out.
// 4-way unrolled independent chains; ascending accum order.
// ---------------------------------------------------------------------------
__global__ __launch_bounds__(256) void k_gather2_out(
    const int* __restrict__ row_ptr, const int* __restrict__ csr,
    const __half* __restrict__ y2h, const __half* __restrict__ z2h,
    const float* __restrict__ bl2, float* __restrict__ out) {
    int wave = threadIdx.x >> 6, lane = threadIdx.x & 63;
    int r = blockIdx.x * 4 + wave;
    if (r >= N_NODES) return;
    int b = row_ptr[r], e = row_ptr[r + 1];
    int g = lane >> 4, l = lane & 15;
    float4 acc = {0.f, 0.f, 0.f, 0.f};
    if (l < 10) {
        union { uint2 u; __half2 h[2]; } c;
        int i = b + g;
        for (; i + 12 < e; i += 16) {
            int sA = csr[i], sB = csr[i + 4], sC = csr[i + 8], sD = csr[i + 12];
            uint2 vA = *(const uint2*)(y2h + ((long)sA << 6) + (l << 2));
            uint2 vB = *(const uint2*)(y2h + ((long)sB << 6) + (l << 2));
            uint2 vC = *(const uint2*)(y2h + ((long)sC << 6) + (l << 2));
            uint2 vD = *(const uint2*)(y2h + ((long)sD << 6) + (l << 2));
            float2 f0, f1;
            c.u = vA; f0 = __half22float2(c.h[0]); f1 = __half22float2(c.h[1]);
            acc.x += f0.x; acc.y += f0.y; acc.z += f1.x; acc.w += f1.y;
            c.u = vB; f0 = __half22float2(c.h[0]); f1 = __half22float2(c.h[1]);
            acc.x += f0.x; acc.y += f0.y; acc.z += f1.x; acc.w += f1.y;
            c.u = vC; f0 = __half22float2(c.h[0]); f1 = __half22float2(c.h[1]);
            acc.x += f0.x; acc.y += f0.y; acc.z += f1.x; acc.w += f1.y;
            c.u = vD; f0 = __half22float2(c.h[0]); f1 = __half22float2(c.h[1]);
            acc.x += f0.x; acc.y += f0.y; acc.z += f1.x; acc.w += f1.y;
        }
        for (; i + 4 < e; i += 8) {
            int sA = csr[i], sB = csr[i + 4];
            uint2 vA = *(const uint2*)(y2h + ((long)sA << 6) + (l << 2));
            uint2 vB = *(const uint2*)(y2h + ((long)sB << 6) + (l << 2));
            float2 f0, f1;
            c.u = vA; f0 = __half22float2(c.h[0]); f1 = __half22float2(c.h[1]);
            acc.x += f0.x; acc.y += f0.y; acc.z += f1.x; acc.w += f1.y;
            c.u = vB; f0 = __half22float2(c.h[0]); f1 = __half22float2(c.h[1]);
            acc.x += f0.x; acc.y += f0.y; acc.z += f1.x; acc.w += f1.y;
        }
        if (i < e) {
            int s = csr[i];
            c.u = *(const uint2*)(y2h + ((long)s << 6) + (l << 2));
            float2 f0 = __half22float2(c.h[0]), f1 = __half22float2(c.h[1]);
            acc.x += f0.x; acc.y += f0.y; acc.z += f1.x; acc.w += f1.y;
        }
    }
    for (int m = 16; m < 64; m <<= 1) {
        acc.x += __shfl_xor(acc.x, m);
        acc.y += __shfl_xor(acc.y, m);
        acc.z += __shfl_xor(acc.z, m);
        acc.w += __shfl_xor(acc.w, m);
    }
    float4 o = {-1e30f, -1e30f, -1e30f, -1e30f};
    if (l < 10) {
        float inv = 1.f / fmaxf((float)(e - b), 1.f);
        union { uint2 u; __half2 h[2]; } cz;
        cz.u = *(const uint2*)(z2h + ((long)r << 6) + (l << 2));
        float2 z0 = __half22float2(cz.h[0]), z1v = __half22float2(cz.h[1]);
        const float4 bb = *(const float4*)(bl2 + (l << 2));
        o.x = acc.x * inv + bb.x + z0.x;
        o.y = acc.y * inv + bb.y + z0.y;
        o.z = acc.z * inv + bb.z + z1v.x;
        o.w = acc.w * inv + bb.w + z1v.y;
    }
    float mx = fmaxf(fmaxf(o.x, o.y), fmaxf(o.z, o.w));
    for (int m = 1; m < 16; m <<= 1) mx = fmaxf(mx, __shfl_xor(mx, m));
    float4 ex;
    ex.x = __expf(o.x - mx); ex.y = __expf(o.y - mx);
    ex.z = __expf(o.z - mx); ex.w = __expf(o.w - mx);
    float sm = ex.x + ex.y + ex.z + ex.w;
    for (int m = 1; m < 16; m <<= 1) sm += __shfl_xor(sm, m);
    if (g == 0 && l < 10) {
        float inv = 1.f / sm;
        float4 res = {ex.x * inv, ex.y * inv, ex.z * inv, ex.w * inv};
        *(float4*)(out + (long)r * C_OUT + (l << 2)) = res;
    }
}

// ---------------------------------------------------------------------------
extern "C" void kernel_launch(void* const* d_in, const int* in_sizes, int n_in,
                              void* d_out, int out_size, void* d_ws,
                              size_t ws_size, hipStream_t stream) {
    const float* x   = (const float*)d_in[0];
    const int*   ei  = (const int*)d_in[1];
    const float* Wl1 = (const float*)d_in[2];
    const float* bl1 = (const float*)d_in[3];
    const float* Wr1 = (const float*)d_in[4];
    const float* Wl2 = (const float*)d_in[5];
    const float* bl2 = (const float*)d_in[6];
    const float* Wr2 = (const float*)d_in[7];
    float* out = (float*)d_out;

    int* bcnt    = (int*)d_ws;                  // 2048
    int* bbase   = bcnt + 2048;                 // 256
    int* row_ptr = bbase + 256;                 // N+4
    int* csr     = row_ptr + N_NODES + 4;       // E
    uintptr_t pa = ((uintptr_t)(csr + N_EDGES) + 127) & ~(uintptr_t)127;
    __half* y1h  = (__half*)pa;                 // N*64 halves (12.8 MB)
    __half* z1h  = y1h + (size_t)N_NODES * 64;  // N*64 halves
    __half* y2h  = z1h + (size_t)N_NODES * 64;  // N*64 halves
    __half* z2h  = y2h + (size_t)N_NODES * 64;  // N*64 halves
    // bucket storage: 19.3 MB, aliases y2h+z2h (25.6 MB); both first written
    // by k_gl2, which runs strictly AFTER k_csr (stream-ordered) -> safe.
    long long* bk = (long long*)y2h;

    hipMemsetAsync(bcnt, 0, NBKT * NSH * sizeof(int), stream);

    k_bscat<<<NTILE, 256, 0, stream>>>(ei, bcnt, bk);
    k_scan_bases<<<1, 256, 0, stream>>>(bcnt, bbase, row_ptr);
    k_csr<<<NBKT, 256, 0, stream>>>(bk, bcnt, bbase, row_ptr, csr);

    const int ntiles = (N_NODES + 63) / 64;
    k_gemm12<<<ntiles, 256, 0, stream>>>(x, Wl1, Wr1, y1h, z1h);
    k_gl2<<<ntiles, 1024, 0, stream>>>(row_ptr, csr, y1h, z1h, bl1, Wl2, Wr2,
                                       y2h, z2h);
    k_gather2_out<<<(N_NODES + 3) / 4, 256, 0, stream>>>(row_ptr, csr, y2h, z2h,
                                                         bl2, out);
}

// Round 21
// 447.415 us; speedup vs baseline: 3.0363x; 3.0363x over previous
//
#include <hip/hip_runtime.h>
#include <hip/hip_fp16.h>

#define N_NODES 100000
#define N_EDGES 1600000
#define C_IN 128
#define C_H 64
#define C_OUT 40

// --- bucketed counting sort params ---
#define BK_SHIFT 9
#define BK_NODES 512
#define NBKT ((N_NODES + BK_NODES - 1) / BK_NODES)   // 196
#define NSH 8
#define CAPS 1536
#define TILE_E 8192
#define NTILE ((N_EDGES + TILE_E - 1) / TILE_E)       // 196
#define EPT 32

#define H_PAD 68
#define W2_PAD 84
#define XH_PAD 136

typedef __attribute__((ext_vector_type(8))) _Float16 f16x8;
typedef __attribute__((ext_vector_type(4))) _Float16 f16x4;
typedef __attribute__((ext_vector_type(4))) float f32x4;

// ---------------------------------------------------------------------------
// K0: block-local binning, then dense run reservation + contiguous writes
// ---------------------------------------------------------------------------
__global__ __launch_bounds__(256) void k_bscat(const int* __restrict__ ei,
                                               int* __restrict__ bcnt,
                                               long long* __restrict__ bk) {
    __shared__ int lcnt[NBKT], lbase[NBKT];
    const int t = threadIdx.x;
    const long e0 = (long)blockIdx.x * TILE_E;
    const int nE = (int)min((long)TILE_E, (long)N_EDGES - e0);
    for (int i = t; i < NBKT; i += 256) lcnt[i] = 0;
    __syncthreads();
    for (int j = 0; j < EPT; ++j) {
        int idx = t + j * 256;
        if (idx < nE) atomicAdd(&lcnt[ei[N_EDGES + e0 + idx] >> BK_SHIFT], 1);
    }
    __syncthreads();
    const int sh = blockIdx.x & (NSH - 1);
    for (int i = t; i < NBKT; i += 256)
        lbase[i] = lcnt[i] ? atomicAdd(&bcnt[i * NSH + sh], lcnt[i]) : 0;
    __syncthreads();
    for (int i = t; i < NBKT; i += 256) lcnt[i] = 0;
    __syncthreads();
    for (int j = 0; j < EPT; ++j) {
        int idx = t + j * 256;
        if (idx < nE) {
            int s = ei[e0 + idx], d = ei[N_EDGES + e0 + idx];
            int b = d >> BK_SHIFT;
            int pos = lbase[b] + atomicAdd(&lcnt[b], 1);
            if (pos < CAPS)
                bk[((long)b * NSH + sh) * CAPS + pos] =
                    ((long long)(d & (BK_NODES - 1)) << 32) | (unsigned)s;
        }
    }
}

__global__ __launch_bounds__(256) void k_scan_bases(const int* __restrict__ bcnt,
                                                    int* __restrict__ bbase,
                                                    int* __restrict__ row_ptr) {
    __shared__ int ls[256];
    int t = threadIdx.x;
    int tot = 0;
    if (t < NBKT)
        for (int j = 0; j < NSH; ++j) tot += min(bcnt[t * NSH + j], CAPS);
    ls[t] = tot;
    __syncthreads();
    for (int off = 1; off < 256; off <<= 1) {
        int u = (t >= off) ? ls[t - off] : 0;
        __syncthreads();
        ls[t] += u;
        __syncthreads();
    }
    if (t < NBKT) bbase[t] = ls[t] - tot;
    if (t == NBKT - 1) row_ptr[N_NODES] = ls[t];
}

__global__ __launch_bounds__(256) void k_csr(const long long* __restrict__ bk,
                                             const int* __restrict__ bcnt,
                                             const int* __restrict__ bbase,
                                             int* __restrict__ row_ptr,
                                             int* __restrict__ csr) {
    __shared__ int deg[BK_NODES], exc[BK_NODES], ctr[BK_NODES];
    __shared__ int ls[256];
    __shared__ int shn[NSH];
    const int b = blockIdx.x, t = threadIdx.x;
    if (t < NSH) shn[t] = min(bcnt[b * NSH + t], CAPS);
    for (int i = t; i < BK_NODES; i += 256) { deg[i] = 0; ctr[i] = 0; }
    __syncthreads();
    for (int j = 0; j < NSH; ++j) {
        const long long* src = bk + ((long)b * NSH + j) * CAPS;
        const int n = shn[j];
        for (int i = t; i < n; i += 256)
            atomicAdd(&deg[(int)(src[i] >> 32)], 1);
    }
    __syncthreads();
    int s0 = deg[2 * t], s1 = deg[2 * t + 1];
    ls[t] = s0 + s1;
    __syncthreads();
    for (int off = 1; off < 256; off <<= 1) {
        int u = (t >= off) ? ls[t - off] : 0;
        __syncthreads();
        ls[t] += u;
        __syncthreads();
    }
    const int tb = ls[t] - (s0 + s1);
    exc[2 * t] = tb;
    exc[2 * t + 1] = tb + s0;
    const int node0 = b * BK_NODES;
    const int gbase = bbase[b];
    if (node0 + 2 * t < N_NODES) row_ptr[node0 + 2 * t] = gbase + tb;
    if (node0 + 2 * t + 1 < N_NODES) row_ptr[node0 + 2 * t + 1] = gbase + tb + s0;
    __syncthreads();
    for (int j = 0; j < NSH; ++j) {
        const long long* src = bk + ((long)b * NSH + j) * CAPS;
        const int n = shn[j];
        for (int i = t; i < n; i += 256) {
            long long v = src[i];
            int dl = (int)(v >> 32);
            int pos = gbase + exc[dl] + atomicAdd(&ctr[dl], 1);
            csr[pos] = (int)(v & 0xffffffffLL);
        }
    }
}

// ---------------------------------------------------------------------------
// K1 (MFMA): y1 = x@Wl1^T (-> fp16)  AND  z1 = x@Wr1^T (-> fp16)
// ---------------------------------------------------------------------------
__global__ __launch_bounds__(256) void k_gemm12(const float* __restrict__ x,
                                                const float* __restrict__ Wl1,
                                                const float* __restrict__ Wr1,
                                                __half* __restrict__ y1h,
                                                __half* __restrict__ z1h) {
    __shared__ _Float16 xs_h[64 * XH_PAD];
    __shared__ _Float16 wl_h[64 * XH_PAD];
    __shared__ _Float16 wr_h[64 * XH_PAD];
    const int tid = threadIdx.x;
    const int r0 = blockIdx.x * 64;
#pragma unroll
    for (int it = 0; it < 8; ++it) {
        int idx = tid * 4 + it * 1024;
        int row = idx >> 7, k = idx & 127;
        int gr = min(r0 + row, N_NODES - 1);
        float4 v = *(const float4*)(x + (long)gr * C_IN + k);
        f16x4 h = {(_Float16)v.x, (_Float16)v.y, (_Float16)v.z, (_Float16)v.w};
        *(f16x4*)(xs_h + row * XH_PAD + k) = h;
    }
#pragma unroll
    for (int it = 0; it < 8; ++it) {
        int idx = tid * 4 + it * 1024;
        int c = idx >> 7, k = idx & 127;
        float4 vl = *(const float4*)(Wl1 + (long)c * C_IN + k);
        float4 vr = *(const float4*)(Wr1 + (long)c * C_IN + k);
        f16x4 hl = {(_Float16)vl.x, (_Float16)vl.y, (_Float16)vl.z, (_Float16)vl.w};
        f16x4 hr = {(_Float16)vr.x, (_Float16)vr.y, (_Float16)vr.z, (_Float16)vr.w};
        *(f16x4*)(wl_h + c * XH_PAD + k) = hl;
        *(f16x4*)(wr_h + c * XH_PAD + k) = hr;
    }
    __syncthreads();
    const int w = tid >> 6, l = tid & 63;
    const int lr = l & 15, kg = l >> 4;
    f16x8 af[4];
#pragma unroll
    for (int kk = 0; kk < 4; ++kk)
        af[kk] = *(const f16x8*)(xs_h + (w * 16 + lr) * XH_PAD + kk * 32 + kg * 8);
    f32x4 acc[8] = {};
#pragma unroll
    for (int t = 0; t < 4; ++t) {
#pragma unroll
        for (int kk = 0; kk < 4; ++kk) {
            f16x8 bl = *(const f16x8*)(wl_h + (t * 16 + lr) * XH_PAD + kk * 32 + kg * 8);
            acc[t] = __builtin_amdgcn_mfma_f32_16x16x32_f16(af[kk], bl, acc[t], 0, 0, 0);
            f16x8 br = *(const f16x8*)(wr_h + (t * 16 + lr) * XH_PAD + kk * 32 + kg * 8);
            acc[4 + t] = __builtin_amdgcn_mfma_f32_16x16x32_f16(af[kk], br, acc[4 + t], 0, 0, 0);
        }
    }
    const int rbase = r0 + w * 16 + kg * 4;
#pragma unroll
    for (int t = 0; t < 4; ++t) {
#pragma unroll
        for (int j = 0; j < 4; ++j) {
            int row = rbase + j;
            if (row < N_NODES) {
                y1h[((long)row << 6) + t * 16 + lr] = __float2half_rn(acc[t][j]);
                z1h[((long)row << 6) + t * 16 + lr] = __float2half_rn(acc[4 + t][j]);
            }
        }
    }
}

// ---------------------------------------------------------------------------
// K2 (FUSED, 256 thr): gather-mean of y1 -> h = relu(mean+bl1+z1) in LDS ->
//                      [y2|z2] = h @ [Wl2^T|Wr2^T]
// 16 nodes/block (4 waves x 4 sequential nodes); 100000/16 = 6250 exact.
// Gather inner loop identical to proven R19 k_gather1 (16 VGPR @ 256 thr).
// LDS = 4.25K (hs) + 21.5K (W2s) = 25.9 KB.
// ---------------------------------------------------------------------------
__global__ __launch_bounds__(256) void k_gl2(
    const int* __restrict__ row_ptr, const int* __restrict__ csr,
    const __half* __restrict__ y1h, const __half* __restrict__ z1h,
    const float* __restrict__ bl1, const float* __restrict__ Wl2,
    const float* __restrict__ Wr2, __half* __restrict__ y2h,
    __half* __restrict__ z2h) {
    __shared__ float hs[16 * H_PAD];      // 4.25 KB
    __shared__ float W2s[C_H * W2_PAD];   // 21.5 KB
    const int tid = threadIdx.x;
    const int r0 = blockIdx.x * 16;
    for (int i = tid; i < C_OUT * C_H; i += 256) {
        int c = i >> 6, k = i & 63;
        W2s[k * W2_PAD + c] = Wl2[i];
        W2s[k * W2_PAD + 40 + c] = Wr2[i];
    }
    const int wave = tid >> 6, lane = tid & 63;
    const int g = lane >> 4, l = lane & 15;
    // ---- gather phase: 4 nodes per wave, sequential ----
    for (int t = 0; t < 4; ++t) {
        int rl = wave * 4 + t;
        int r = r0 + rl;
        if (r >= N_NODES) break;
        int b = row_ptr[r], e = row_ptr[r + 1];
        float4 acc = {0.f, 0.f, 0.f, 0.f};
        union { uint2 u; __half2 h[2]; } c;
        int i = b + g;
        for (; i + 12 < e; i += 16) {
            int sA = csr[i], sB = csr[i + 4], sC = csr[i + 8], sD = csr[i + 12];
            uint2 vA = *(const uint2*)(y1h + ((long)sA << 6) + (l << 2));
            uint2 vB = *(const uint2*)(y1h + ((long)sB << 6) + (l << 2));
            uint2 vC = *(const uint2*)(y1h + ((long)sC << 6) + (l << 2));
            uint2 vD = *(const uint2*)(y1h + ((long)sD << 6) + (l << 2));
            float2 f0, f1;
            c.u = vA; f0 = __half22float2(c.h[0]); f1 = __half22float2(c.h[1]);
            acc.x += f0.x; acc.y += f0.y; acc.z += f1.x; acc.w += f1.y;
            c.u = vB; f0 = __half22float2(c.h[0]); f1 = __half22float2(c.h[1]);
            acc.x += f0.x; acc.y += f0.y; acc.z += f1.x; acc.w += f1.y;
            c.u = vC; f0 = __half22float2(c.h[0]); f1 = __half22float2(c.h[1]);
            acc.x += f0.x; acc.y += f0.y; acc.z += f1.x; acc.w += f1.y;
            c.u = vD; f0 = __half22float2(c.h[0]); f1 = __half22float2(c.h[1]);
            acc.x += f0.x; acc.y += f0.y; acc.z += f1.x; acc.w += f1.y;
        }
        for (; i + 4 < e; i += 8) {
            int sA = csr[i], sB = csr[i + 4];
            uint2 vA = *(const uint2*)(y1h + ((long)sA << 6) + (l << 2));
            uint2 vB = *(const uint2*)(y1h + ((long)sB << 6) + (l << 2));
            float2 f0, f1;
            c.u = vA; f0 = __half22float2(c.h[0]); f1 = __half22float2(c.h[1]);
            acc.x += f0.x; acc.y += f0.y; acc.z += f1.x; acc.w += f1.y;
            c.u = vB; f0 = __half22float2(c.h[0]); f1 = __half22float2(c.h[1]);
            acc.x += f0.x; acc.y += f0.y; acc.z += f1.x; acc.w += f1.y;
        }
        if (i < e) {
            int s = csr[i];
            c.u = *(const uint2*)(y1h + ((long)s << 6) + (l << 2));
            float2 f0 = __half22float2(c.h[0]), f1 = __half22float2(c.h[1]);
            acc.x += f0.x; acc.y += f0.y; acc.z += f1.x; acc.w += f1.y;
        }
        for (int m = 16; m < 64; m <<= 1) {
            acc.x += __shfl_xor(acc.x, m);
            acc.y += __shfl_xor(acc.y, m);
            acc.z += __shfl_xor(acc.z, m);
            acc.w += __shfl_xor(acc.w, m);
        }
        if (g == 0) {
            float inv = 1.f / fmaxf((float)(e - b), 1.f);
            union { uint2 u; __half2 h[2]; } cz;
            cz.u = *(const uint2*)(z1h + ((long)r << 6) + (l << 2));
            float2 z0 = __half22float2(cz.h[0]), z1v = __half22float2(cz.h[1]);
            const float4 bb = *(const float4*)(bl1 + (l << 2));
            float4 h;
            h.x = fmaxf(acc.x * inv + bb.x + z0.x, 0.f);
            h.y = fmaxf(acc.y * inv + bb.y + z0.y, 0.f);
            h.z = fmaxf(acc.z * inv + bb.z + z1v.x, 0.f);
            h.w = fmaxf(acc.w * inv + bb.w + z1v.y, 0.f);
            *(float4*)(hs + rl * H_PAD + (l << 2)) = h;
        }
    }
    __syncthreads();
    // ---- phase 2: [y2|z2] = h @ [Wl2^T|Wr2^T]; 1 row x 5 cols per thread ----
    {
        const int row_l = tid >> 4, tj = tid & 15;
        float acc[5] = {};
        for (int k0 = 0; k0 < C_H; k0 += 4) {
            float4 hr = *(const float4*)(hs + row_l * H_PAD + k0);
            const float* hp = (const float*)&hr;
#pragma unroll
            for (int kk = 0; kk < 4; ++kk) {
                float hv = hp[kk];
#pragma unroll
                for (int cc = 0; cc < 5; ++cc)
                    acc[cc] = fmaf(hv, W2s[(k0 + kk) * W2_PAD + tj * 5 + cc], acc[cc]);
            }
        }
        int row = r0 + row_l;
        if (row < N_NODES) {
#pragma unroll
            for (int cc = 0; cc < 5; ++cc) {
                int cidx = tj * 5 + cc;
                if (cidx < C_OUT)
                    y2h[((long)row << 6) + cidx] = __float2half_rn(acc[cc]);
                else
                    z2h[((long)row << 6) + (cidx - C_OUT)] = __float2half_rn(acc[cc]);
            }
        }
    }
}

// ---------------------------------------------------------------------------
// K3: fused gather-mean of y2 + bias + z2 (fp16) + softmax -> out.
// 4-way unrolled independent chains; ascending accum order.
// ---------------------------------------------------------------------------
__global__ __launch_bounds__(256) void k_gather2_out(
    const int* __restrict__ row_ptr, const int* __restrict__ csr,
    const __half* __restrict__ y2h, const __half* __restrict__ z2h,
    const float* __restrict__ bl2, float* __restrict__ out) {
    int wave = threadIdx.x >> 6, lane = threadIdx.x & 63;
    int r = blockIdx.x * 4 + wave;
    if (r >= N_NODES) return;
    int b = row_ptr[r], e = row_ptr[r + 1];
    int g = lane >> 4, l = lane & 15;
    float4 acc = {0.f, 0.f, 0.f, 0.f};
    if (l < 10) {
        union { uint2 u; __half2 h[2]; } c;
        int i = b + g;
        for (; i + 12 < e; i += 16) {
            int sA = csr[i], sB = csr[i + 4], sC = csr[i + 8], sD = csr[i + 12];
            uint2 vA = *(const uint2*)(y2h + ((long)sA << 6) + (l << 2));
            uint2 vB = *(const uint2*)(y2h + ((long)sB << 6) + (l << 2));
            uint2 vC = *(const uint2*)(y2h + ((long)sC << 6) + (l << 2));
            uint2 vD = *(const uint2*)(y2h + ((long)sD << 6) + (l << 2));
            float2 f0, f1;
            c.u = vA; f0 = __half22float2(c.h[0]); f1 = __half22float2(c.h[1]);
            acc.x += f0.x; acc.y += f0.y; acc.z += f1.x; acc.w += f1.y;
            c.u = vB; f0 = __half22float2(c.h[0]); f1 = __half22float2(c.h[1]);
            acc.x += f0.x; acc.y += f0.y; acc.z += f1.x; acc.w += f1.y;
            c.u = vC; f0 = __half22float2(c.h[0]); f1 = __half22float2(c.h[1]);
            acc.x += f0.x; acc.y += f0.y; acc.z += f1.x; acc.w += f1.y;
            c.u = vD; f0 = __half22float2(c.h[0]); f1 = __half22float2(c.h[1]);
            acc.x += f0.x; acc.y += f0.y; acc.z += f1.x; acc.w += f1.y;
        }
        for (; i + 4 < e; i += 8) {
            int sA = csr[i], sB = csr[i + 4];
            uint2 vA = *(const uint2*)(y2h + ((long)sA << 6) + (l << 2));
            uint2 vB = *(const uint2*)(y2h + ((long)sB << 6) + (l << 2));
            float2 f0, f1;
            c.u = vA; f0 = __half22float2(c.h[0]); f1 = __half22float2(c.h[1]);
            acc.x += f0.x; acc.y += f0.y; acc.z += f1.x; acc.w += f1.y;
            c.u = vB; f0 = __half22float2(c.h[0]); f1 = __half22float2(c.h[1]);
            acc.x += f0.x; acc.y += f0.y; acc.z += f1.x; acc.w += f1.y;
        }
        if (i < e) {
            int s = csr[i];
            c.u = *(const uint2*)(y2h + ((long)s << 6) + (l << 2));
            float2 f0 = __half22float2(c.h[0]), f1 = __half22float2(c.h[1]);
            acc.x += f0.x; acc.y += f0.y; acc.z += f1.x; acc.w += f1.y;
        }
    }
    for (int m = 16; m < 64; m <<= 1) {
        acc.x += __shfl_xor(acc.x, m);
        acc.y += __shfl_xor(acc.y, m);
        acc.z += __shfl_xor(acc.z, m);
        acc.w += __shfl_xor(acc.w, m);
    }
    float4 o = {-1e30f, -1e30f, -1e30f, -1e30f};
    if (l < 10) {
        float inv = 1.f / fmaxf((float)(e - b), 1.f);
        union { uint2 u; __half2 h[2]; } cz;
        cz.u = *(const uint2*)(z2h + ((long)r << 6) + (l << 2));
        float2 z0 = __half22float2(cz.h[0]), z1v = __half22float2(cz.h[1]);
        const float4 bb = *(const float4*)(bl2 + (l << 2));
        o.x = acc.x * inv + bb.x + z0.x;
        o.y = acc.y * inv + bb.y + z0.y;
        o.z = acc.z * inv + bb.z + z1v.x;
        o.w = acc.w * inv + bb.w + z1v.y;
    }
    float mx = fmaxf(fmaxf(o.x, o.y), fmaxf(o.z, o.w));
    for (int m = 1; m < 16; m <<= 1) mx = fmaxf(mx, __shfl_xor(mx, m));
    float4 ex;
    ex.x = __expf(o.x - mx); ex.y = __expf(o.y - mx);
    ex.z = __expf(o.z - mx); ex.w = __expf(o.w - mx);
    float sm = ex.x + ex.y + ex.z + ex.w;
    for (int m = 1; m < 16; m <<= 1) sm += __shfl_xor(sm, m);
    if (g == 0 && l < 10) {
        float inv = 1.f / sm;
        float4 res = {ex.x * inv, ex.y * inv, ex.z * inv, ex.w * inv};
        *(float4*)(out + (long)r * C_OUT + (l << 2)) = res;
    }
}

// ---------------------------------------------------------------------------
extern "C" void kernel_launch(void* const* d_in, const int* in_sizes, int n_in,
                              void* d_out, int out_size, void* d_ws,
                              size_t ws_size, hipStream_t stream) {
    const float* x   = (const float*)d_in[0];
    const int*   ei  = (const int*)d_in[1];
    const float* Wl1 = (const float*)d_in[2];
    const float* bl1 = (const float*)d_in[3];
    const float* Wr1 = (const float*)d_in[4];
    const float* Wl2 = (const float*)d_in[5];
    const float* bl2 = (const float*)d_in[6];
    const float* Wr2 = (const float*)d_in[7];
    float* out = (float*)d_out;

    int* bcnt    = (int*)d_ws;                  // 2048
    int* bbase   = bcnt + 2048;                 // 256
    int* row_ptr = bbase + 256;                 // N+4
    int* csr     = row_ptr + N_NODES + 4;       // E
    uintptr_t pa = ((uintptr_t)(csr + N_EDGES) + 127) & ~(uintptr_t)127;
    __half* y1h  = (__half*)pa;                 // N*64 halves (12.8 MB)
    __half* z1h  = y1h + (size_t)N_NODES * 64;  // N*64 halves
    __half* y2h  = z1h + (size_t)N_NODES * 64;  // N*64 halves
    __half* z2h  = y2h + (size_t)N_NODES * 64;  // N*64 halves
    // bucket storage: 19.3 MB, aliases y2h+z2h (25.6 MB); both first written
    // by k_gl2, which runs strictly AFTER k_csr (stream-ordered) -> safe.
    long long* bk = (long long*)y2h;

    hipMemsetAsync(bcnt, 0, NBKT * NSH * sizeof(int), stream);

    k_bscat<<<NTILE, 256, 0, stream>>>(ei, bcnt, bk);
    k_scan_bases<<<1, 256, 0, stream>>>(bcnt, bbase, row_ptr);
    k_csr<<<NBKT, 256, 0, stream>>>(bk, bcnt, bbase, row_ptr, csr);

    const int ntiles = (N_NODES + 63) / 64;
    k_gemm12<<<ntiles, 256, 0, stream>>>(x, Wl1, Wr1, y1h, z1h);
    k_gl2<<<(N_NODES + 15) / 16, 256, 0, stream>>>(row_ptr, csr, y1h, z1h, bl1,
                                                   Wl2, Wr2, y2h, z2h);
    k_gather2_out<<<(N_NODES + 3) / 4, 256, 0, stream>>>(row_ptr, csr, y2h, z2h,
                                                         bl2, out);
}

// Round 22
// 205.635 us; speedup vs baseline: 6.6062x; 2.1758x over previous
//
#include <hip/hip_runtime.h>
#include <hip/hip_fp16.h>

#define N_NODES 100000
#define N_EDGES 1600000
#define C_IN 128
#define C_H 64
#define C_OUT 40

// --- bucketed counting sort params ---
#define BK_SHIFT 9
#define BK_NODES 512
#define NBKT ((N_NODES + BK_NODES - 1) / BK_NODES)   // 196
#define NSH 8
#define CAPS 1536
#define TILE_E 8192
#define NTILE ((N_EDGES + TILE_E - 1) / TILE_E)       // 196
#define EPT 32

#define H_PAD 68
#define W2_PAD 84
#define XH_PAD 136

typedef __attribute__((ext_vector_type(8))) _Float16 f16x8;
typedef __attribute__((ext_vector_type(4))) _Float16 f16x4;
typedef __attribute__((ext_vector_type(4))) float f32x4;

// ---------------------------------------------------------------------------
// K0: block-local binning, then dense run reservation + contiguous writes
// ---------------------------------------------------------------------------
__global__ __launch_bounds__(256) void k_bscat(const int* __restrict__ ei,
                                               int* __restrict__ bcnt,
                                               long long* __restrict__ bk) {
    __shared__ int lcnt[NBKT], lbase[NBKT];
    const int t = threadIdx.x;
    const long e0 = (long)blockIdx.x * TILE_E;
    const int nE = (int)min((long)TILE_E, (long)N_EDGES - e0);
    for (int i = t; i < NBKT; i += 256) lcnt[i] = 0;
    __syncthreads();
    for (int j = 0; j < EPT; ++j) {
        int idx = t + j * 256;
        if (idx < nE) atomicAdd(&lcnt[ei[N_EDGES + e0 + idx] >> BK_SHIFT], 1);
    }
    __syncthreads();
    const int sh = blockIdx.x & (NSH - 1);
    for (int i = t; i < NBKT; i += 256)
        lbase[i] = lcnt[i] ? atomicAdd(&bcnt[i * NSH + sh], lcnt[i]) : 0;
    __syncthreads();
    for (int i = t; i < NBKT; i += 256) lcnt[i] = 0;
    __syncthreads();
    for (int j = 0; j < EPT; ++j) {
        int idx = t + j * 256;
        if (idx < nE) {
            int s = ei[e0 + idx], d = ei[N_EDGES + e0 + idx];
            int b = d >> BK_SHIFT;
            int pos = lbase[b] + atomicAdd(&lcnt[b], 1);
            if (pos < CAPS)
                bk[((long)b * NSH + sh) * CAPS + pos] =
                    ((long long)(d & (BK_NODES - 1)) << 32) | (unsigned)s;
        }
    }
}

__global__ __launch_bounds__(256) void k_scan_bases(const int* __restrict__ bcnt,
                                                    int* __restrict__ bbase,
                                                    int* __restrict__ row_ptr) {
    __shared__ int ls[256];
    int t = threadIdx.x;
    int tot = 0;
    if (t < NBKT)
        for (int j = 0; j < NSH; ++j) tot += min(bcnt[t * NSH + j], CAPS);
    ls[t] = tot;
    __syncthreads();
    for (int off = 1; off < 256; off <<= 1) {
        int u = (t >= off) ? ls[t - off] : 0;
        __syncthreads();
        ls[t] += u;
        __syncthreads();
    }
    if (t < NBKT) bbase[t] = ls[t] - tot;
    if (t == NBKT - 1) row_ptr[N_NODES] = ls[t];
}

__global__ __launch_bounds__(256) void k_csr(const long long* __restrict__ bk,
                                             const int* __restrict__ bcnt,
                                             const int* __restrict__ bbase,
                                             int* __restrict__ row_ptr,
                                             int* __restrict__ csr) {
    __shared__ int deg[BK_NODES], exc[BK_NODES], ctr[BK_NODES];
    __shared__ int ls[256];
    __shared__ int shn[NSH];
    const int b = blockIdx.x, t = threadIdx.x;
    if (t < NSH) shn[t] = min(bcnt[b * NSH + t], CAPS);
    for (int i = t; i < BK_NODES; i += 256) { deg[i] = 0; ctr[i] = 0; }
    __syncthreads();
    for (int j = 0; j < NSH; ++j) {
        const long long* src = bk + ((long)b * NSH + j) * CAPS;
        const int n = shn[j];
        for (int i = t; i < n; i += 256)
            atomicAdd(&deg[(int)(src[i] >> 32)], 1);
    }
    __syncthreads();
    int s0 = deg[2 * t], s1 = deg[2 * t + 1];
    ls[t] = s0 + s1;
    __syncthreads();
    for (int off = 1; off < 256; off <<= 1) {
        int u = (t >= off) ? ls[t - off] : 0;
        __syncthreads();
        ls[t] += u;
        __syncthreads();
    }
    const int tb = ls[t] - (s0 + s1);
    exc[2 * t] = tb;
    exc[2 * t + 1] = tb + s0;
    const int node0 = b * BK_NODES;
    const int gbase = bbase[b];
    if (node0 + 2 * t < N_NODES) row_ptr[node0 + 2 * t] = gbase + tb;
    if (node0 + 2 * t + 1 < N_NODES) row_ptr[node0 + 2 * t + 1] = gbase + tb + s0;
    __syncthreads();
    for (int j = 0; j < NSH; ++j) {
        const long long* src = bk + ((long)b * NSH + j) * CAPS;
        const int n = shn[j];
        for (int i = t; i < n; i += 256) {
            long long v = src[i];
            int dl = (int)(v >> 32);
            int pos = gbase + exc[dl] + atomicAdd(&ctr[dl], 1);
            csr[pos] = (int)(v & 0xffffffffLL);
        }
    }
}

// ---------------------------------------------------------------------------
// K1 (MFMA): y1 = x@Wl1^T (-> fp16)  AND  z1 = x@Wr1^T (-> fp16)
// ---------------------------------------------------------------------------
__global__ __launch_bounds__(256) void k_gemm12(const float* __restrict__ x,
                                                const float* __restrict__ Wl1,
                                                const float* __restrict__ Wr1,
                                                __half* __restrict__ y1h,
                                                __half* __restrict__ z1h) {
    __shared__ _Float16 xs_h[64 * XH_PAD];
    __shared__ _Float16 wl_h[64 * XH_PAD];
    __shared__ _Float16 wr_h[64 * XH_PAD];
    const int tid = threadIdx.x;
    const int r0 = blockIdx.x * 64;
#pragma unroll
    for (int it = 0; it < 8; ++it) {
        int idx = tid * 4 + it * 1024;
        int row = idx >> 7, k = idx & 127;
        int gr = min(r0 + row, N_NODES - 1);
        float4 v = *(const float4*)(x + (long)gr * C_IN + k);
        f16x4 h = {(_Float16)v.x, (_Float16)v.y, (_Float16)v.z, (_Float16)v.w};
        *(f16x4*)(xs_h + row * XH_PAD + k) = h;
    }
#pragma unroll
    for (int it = 0; it < 8; ++it) {
        int idx = tid * 4 + it * 1024;
        int c = idx >> 7, k = idx & 127;
        float4 vl = *(const float4*)(Wl1 + (long)c * C_IN + k);
        float4 vr = *(const float4*)(Wr1 + (long)c * C_IN + k);
        f16x4 hl = {(_Float16)vl.x, (_Float16)vl.y, (_Float16)vl.z, (_Float16)vl.w};
        f16x4 hr = {(_Float16)vr.x, (_Float16)vr.y, (_Float16)vr.z, (_Float16)vr.w};
        *(f16x4*)(wl_h + c * XH_PAD + k) = hl;
        *(f16x4*)(wr_h + c * XH_PAD + k) = hr;
    }
    __syncthreads();
    const int w = tid >> 6, l = tid & 63;
    const int lr = l & 15, kg = l >> 4;
    f16x8 af[4];
#pragma unroll
    for (int kk = 0; kk < 4; ++kk)
        af[kk] = *(const f16x8*)(xs_h + (w * 16 + lr) * XH_PAD + kk * 32 + kg * 8);
    f32x4 acc[8] = {};
#pragma unroll
    for (int t = 0; t < 4; ++t) {
#pragma unroll
        for (int kk = 0; kk < 4; ++kk) {
            f16x8 bl = *(const f16x8*)(wl_h + (t * 16 + lr) * XH_PAD + kk * 32 + kg * 8);
            acc[t] = __builtin_amdgcn_mfma_f32_16x16x32_f16(af[kk], bl, acc[t], 0, 0, 0);
            f16x8 br = *(const f16x8*)(wr_h + (t * 16 + lr) * XH_PAD + kk * 32 + kg * 8);
            acc[4 + t] = __builtin_amdgcn_mfma_f32_16x16x32_f16(af[kk], br, acc[4 + t], 0, 0, 0);
        }
    }
    const int rbase = r0 + w * 16 + kg * 4;
#pragma unroll
    for (int t = 0; t < 4; ++t) {
#pragma unroll
        for (int j = 0; j < 4; ++j) {
            int row = rbase + j;
            if (row < N_NODES) {
                y1h[((long)row << 6) + t * 16 + lr] = __float2half_rn(acc[t][j]);
                z1h[((long)row << 6) + t * 16 + lr] = __float2half_rn(acc[4 + t][j]);
            }
        }
    }
}

// ---------------------------------------------------------------------------
// K2: mean1[r] = mean_{s in N(r)} y1[s]  -> fp16 m1h
// 4-way unrolled independent (csr -> row) chains; ascending accum order.
// ---------------------------------------------------------------------------
__global__ __launch_bounds__(256) void k_gather1(const int* __restrict__ row_ptr,
                                                 const int* __restrict__ csr,
                                                 const __half* __restrict__ y1h,
                                                 __half* __restrict__ m1h) {
    int wave = threadIdx.x >> 6, lane = threadIdx.x & 63;
    int r = blockIdx.x * 4 + wave;
    if (r >= N_NODES) return;
    int b = row_ptr[r], e = row_ptr[r + 1];
    int g = lane >> 4, l = lane & 15;
    float4 acc = {0.f, 0.f, 0.f, 0.f};
    union { uint2 u; __half2 h[2]; } c;
    int i = b + g;
    for (; i + 12 < e; i += 16) {
        int sA = csr[i], sB = csr[i + 4], sC = csr[i + 8], sD = csr[i + 12];
        uint2 vA = *(const uint2*)(y1h + ((long)sA << 6) + (l << 2));
        uint2 vB = *(const uint2*)(y1h + ((long)sB << 6) + (l << 2));
        uint2 vC = *(const uint2*)(y1h + ((long)sC << 6) + (l << 2));
        uint2 vD = *(const uint2*)(y1h + ((long)sD << 6) + (l << 2));
        float2 f0, f1;
        c.u = vA; f0 = __half22float2(c.h[0]); f1 = __half22float2(c.h[1]);
        acc.x += f0.x; acc.y += f0.y; acc.z += f1.x; acc.w += f1.y;
        c.u = vB; f0 = __half22float2(c.h[0]); f1 = __half22float2(c.h[1]);
        acc.x += f0.x; acc.y += f0.y; acc.z += f1.x; acc.w += f1.y;
        c.u = vC; f0 = __half22float2(c.h[0]); f1 = __half22float2(c.h[1]);
        acc.x += f0.x; acc.y += f0.y; acc.z += f1.x; acc.w += f1.y;
        c.u = vD; f0 = __half22float2(c.h[0]); f1 = __half22float2(c.h[1]);
        acc.x += f0.x; acc.y += f0.y; acc.z += f1.x; acc.w += f1.y;
    }
    for (; i + 4 < e; i += 8) {
        int sA = csr[i], sB = csr[i + 4];
        uint2 vA = *(const uint2*)(y1h + ((long)sA << 6) + (l << 2));
        uint2 vB = *(const uint2*)(y1h + ((long)sB << 6) + (l << 2));
        float2 f0, f1;
        c.u = vA; f0 = __half22float2(c.h[0]); f1 = __half22float2(c.h[1]);
        acc.x += f0.x; acc.y += f0.y; acc.z += f1.x; acc.w += f1.y;
        c.u = vB; f0 = __half22float2(c.h[0]); f1 = __half22float2(c.h[1]);
        acc.x += f0.x; acc.y += f0.y; acc.z += f1.x; acc.w += f1.y;
    }
    if (i < e) {
        int s = csr[i];
        c.u = *(const uint2*)(y1h + ((long)s << 6) + (l << 2));
        float2 f0 = __half22float2(c.h[0]), f1 = __half22float2(c.h[1]);
        acc.x += f0.x; acc.y += f0.y; acc.z += f1.x; acc.w += f1.y;
    }
    for (int m = 16; m < 64; m <<= 1) {
        acc.x += __shfl_xor(acc.x, m);
        acc.y += __shfl_xor(acc.y, m);
        acc.z += __shfl_xor(acc.z, m);
        acc.w += __shfl_xor(acc.w, m);
    }
    if (g == 0) {
        float inv = 1.f / fmaxf((float)(e - b), 1.f);
        union { uint2 u; __half2 h[2]; } w;
        w.h[0] = __floats2half2_rn(acc.x * inv, acc.y * inv);
        w.h[1] = __floats2half2_rn(acc.z * inv, acc.w * inv);
        *(uint2*)(m1h + ((long)r << 6) + (l << 2)) = w.u;
    }
}

// ---------------------------------------------------------------------------
// K3: h = relu(m1h + bl1 + z1h) ; [y2|z2] = h @ [Wl2^T|Wr2^T]
//     y2 -> fp16 (64-half rows), z2 -> fp16 (64-half rows)
// ---------------------------------------------------------------------------
__global__ __launch_bounds__(256) void k_l2fin(
    const __half* __restrict__ z1h, const __half* __restrict__ m1h,
    const float* __restrict__ bl1, const float* __restrict__ Wl2,
    const float* __restrict__ Wr2, __half* __restrict__ y2h,
    __half* __restrict__ z2h) {
    __shared__ float hs[64 * H_PAD];
    __shared__ float W2s[C_H * W2_PAD];
    const int tid = threadIdx.x;
    const int r0 = blockIdx.x * 64;
    for (int i = tid; i < C_OUT * C_H; i += 256) {
        int c = i >> 6, k = i & 63;
        W2s[k * W2_PAD + c] = Wl2[i];
        W2s[k * W2_PAD + 40 + c] = Wr2[i];
    }
    const int ti = tid >> 4, tj = tid & 15;
    {
        const float4 bb = *(const float4*)(bl1 + tj * 4);
#pragma unroll
        for (int rr = 0; rr < 4; ++rr) {
            int gr = min(r0 + ti * 4 + rr, N_NODES - 1);
            union { uint2 u; __half2 h[2]; } cz, cm;
            cz.u = *(const uint2*)(z1h + ((long)gr << 6) + tj * 4);
            cm.u = *(const uint2*)(m1h + ((long)gr << 6) + tj * 4);
            float2 z0 = __half22float2(cz.h[0]), z1v = __half22float2(cz.h[1]);
            float2 m0 = __half22float2(cm.h[0]), m1v = __half22float2(cm.h[1]);
            float4 h;
            h.x = fmaxf(z0.x + m0.x + bb.x, 0.f);
            h.y = fmaxf(z0.y + m0.y + bb.y, 0.f);
            h.z = fmaxf(z1v.x + m1v.x + bb.z, 0.f);
            h.w = fmaxf(z1v.y + m1v.y + bb.w, 0.f);
            *(float4*)(hs + (ti * 4 + rr) * H_PAD + tj * 4) = h;
        }
    }
    __syncthreads();
    {
        float acc[4][5] = {};
        for (int k0 = 0; k0 < C_H; k0 += 4) {
            float4 hr[4];
#pragma unroll
            for (int rr = 0; rr < 4; ++rr)
                hr[rr] = *(const float4*)(hs + (ti * 4 + rr) * H_PAD + k0);
            float wv[4][5];
#pragma unroll
            for (int kk = 0; kk < 4; ++kk)
#pragma unroll
                for (int cc = 0; cc < 5; ++cc)
                    wv[kk][cc] = W2s[(k0 + kk) * W2_PAD + tj * 5 + cc];
#pragma unroll
            for (int rr = 0; rr < 4; ++rr) {
                const float* hp = (const float*)&hr[rr];
#pragma unroll
                for (int kk = 0; kk < 4; ++kk) {
                    float hv = hp[kk];
#pragma unroll
                    for (int cc = 0; cc < 5; ++cc)
                        acc[rr][cc] = fmaf(hv, wv[kk][cc], acc[rr][cc]);
                }
            }
        }
#pragma unroll
        for (int rr = 0; rr < 4; ++rr) {
            int row = r0 + ti * 4 + rr;
            if (row < N_NODES) {
#pragma unroll
                for (int cc = 0; cc < 5; ++cc) {
                    int c = tj * 5 + cc;
                    if (c < C_OUT)
                        y2h[((long)row << 6) + c] = __float2half_rn(acc[rr][cc]);
                    else
                        z2h[((long)row << 6) + (c - C_OUT)] = __float2half_rn(acc[rr][cc]);
                }
            }
        }
    }
}

// ---------------------------------------------------------------------------
// K4: fused gather-mean of y2 + bias + z2 (fp16) + softmax -> out.
// 4-way unrolled independent chains; ascending accum order.
// ---------------------------------------------------------------------------
__global__ __launch_bounds__(256) void k_gather2_out(
    const int* __restrict__ row_ptr, const int* __restrict__ csr,
    const __half* __restrict__ y2h, const __half* __restrict__ z2h,
    const float* __restrict__ bl2, float* __restrict__ out) {
    int wave = threadIdx.x >> 6, lane = threadIdx.x & 63;
    int r = blockIdx.x * 4 + wave;
    if (r >= N_NODES) return;
    int b = row_ptr[r], e = row_ptr[r + 1];
    int g = lane >> 4, l = lane & 15;
    float4 acc = {0.f, 0.f, 0.f, 0.f};
    if (l < 10) {
        union { uint2 u; __half2 h[2]; } c;
        int i = b + g;
        for (; i + 12 < e; i += 16) {
            int sA = csr[i], sB = csr[i + 4], sC = csr[i + 8], sD = csr[i + 12];
            uint2 vA = *(const uint2*)(y2h + ((long)sA << 6) + (l << 2));
            uint2 vB = *(const uint2*)(y2h + ((long)sB << 6) + (l << 2));
            uint2 vC = *(const uint2*)(y2h + ((long)sC << 6) + (l << 2));
            uint2 vD = *(const uint2*)(y2h + ((long)sD << 6) + (l << 2));
            float2 f0, f1;
            c.u = vA; f0 = __half22float2(c.h[0]); f1 = __half22float2(c.h[1]);
            acc.x += f0.x; acc.y += f0.y; acc.z += f1.x; acc.w += f1.y;
            c.u = vB; f0 = __half22float2(c.h[0]); f1 = __half22float2(c.h[1]);
            acc.x += f0.x; acc.y += f0.y; acc.z += f1.x; acc.w += f1.y;
            c.u = vC; f0 = __half22float2(c.h[0]); f1 = __half22float2(c.h[1]);
            acc.x += f0.x; acc.y += f0.y; acc.z += f1.x; acc.w += f1.y;
            c.u = vD; f0 = __half22float2(c.h[0]); f1 = __half22float2(c.h[1]);
            acc.x += f0.x; acc.y += f0.y; acc.z += f1.x; acc.w += f1.y;
        }
        for (; i + 4 < e; i += 8) {
            int sA = csr[i], sB = csr[i + 4];
            uint2 vA = *(const uint2*)(y2h + ((long)sA << 6) + (l << 2));
            uint2 vB = *(const uint2*)(y2h + ((long)sB << 6) + (l << 2));
            float2 f0, f1;
            c.u = vA; f0 = __half22float2(c.h[0]); f1 = __half22float2(c.h[1]);
            acc.x += f0.x; acc.y += f0.y; acc.z += f1.x; acc.w += f1.y;
            c.u = vB; f0 = __half22float2(c.h[0]); f1 = __half22float2(c.h[1]);
            acc.x += f0.x; acc.y += f0.y; acc.z += f1.x; acc.w += f1.y;
        }
        if (i < e) {
            int s = csr[i];
            c.u = *(const uint2*)(y2h + ((long)s << 6) + (l << 2));
            float2 f0 = __half22float2(c.h[0]), f1 = __half22float2(c.h[1]);
            acc.x += f0.x; acc.y += f0.y; acc.z += f1.x; acc.w += f1.y;
        }
    }
    for (int m = 16; m < 64; m <<= 1) {
        acc.x += __shfl_xor(acc.x, m);
        acc.y += __shfl_xor(acc.y, m);
        acc.z += __shfl_xor(acc.z, m);
        acc.w += __shfl_xor(acc.w, m);
    }
    float4 o = {-1e30f, -1e30f, -1e30f, -1e30f};
    if (l < 10) {
        float inv = 1.f / fmaxf((float)(e - b), 1.f);
        union { uint2 u; __half2 h[2]; } cz;
        cz.u = *(const uint2*)(z2h + ((long)r << 6) + (l << 2));
        float2 z0 = __half22float2(cz.h[0]), z1v = __half22float2(cz.h[1]);
        const float4 bb = *(const float4*)(bl2 + (l << 2));
        o.x = acc.x * inv + bb.x + z0.x;
        o.y = acc.y * inv + bb.y + z0.y;
        o.z = acc.z * inv + bb.z + z1v.x;
        o.w = acc.w * inv + bb.w + z1v.y;
    }
    float mx = fmaxf(fmaxf(o.x, o.y), fmaxf(o.z, o.w));
    for (int m = 1; m < 16; m <<= 1) mx = fmaxf(mx, __shfl_xor(mx, m));
    float4 ex;
    ex.x = __expf(o.x - mx); ex.y = __expf(o.y - mx);
    ex.z = __expf(o.z - mx); ex.w = __expf(o.w - mx);
    float sm = ex.x + ex.y + ex.z + ex.w;
    for (int m = 1; m < 16; m <<= 1) sm += __shfl_xor(sm, m);
    if (g == 0 && l < 10) {
        float inv = 1.f / sm;
        float4 res = {ex.x * inv, ex.y * inv, ex.z * inv, ex.w * inv};
        *(float4*)(out + (long)r * C_OUT + (l << 2)) = res;
    }
}

// ---------------------------------------------------------------------------
extern "C" void kernel_launch(void* const* d_in, const int* in_sizes, int n_in,
                              void* d_out, int out_size, void* d_ws,
                              size_t ws_size, hipStream_t stream) {
    const float* x   = (const float*)d_in[0];
    const int*   ei  = (const int*)d_in[1];
    const float* Wl1 = (const float*)d_in[2];
    const float* bl1 = (const float*)d_in[3];
    const float* Wr1 = (const float*)d_in[4];
    const float* Wl2 = (const float*)d_in[5];
    const float* bl2 = (const float*)d_in[6];
    const float* Wr2 = (const float*)d_in[7];
    float* out = (float*)d_out;

    int* bcnt    = (int*)d_ws;                  // 2048
    int* bbase   = bcnt + 2048;                 // 256
    int* row_ptr = bbase + 256;                 // N+4
    int* csr     = row_ptr + N_NODES + 4;       // E
    uintptr_t pa = ((uintptr_t)(csr + N_EDGES) + 127) & ~(uintptr_t)127;
    __half* y1h  = (__half*)pa;                 // N*64 halves (12.8 MB)
    __half* y2h  = y1h;                         // alias: y1h dead after gather1
    __half* m1h  = y1h + (size_t)N_NODES * 64;  // N*64 halves
    __half* z1h  = m1h + (size_t)N_NODES * 64;  // N*64 halves
    __half* z2h  = z1h + (size_t)N_NODES * 64;  // N*64 halves
    // bucket storage: 19.3 MB, aliases m1h+z1h (25.6 MB); both first written
    // AFTER k_csr completes (gemm12 -> z1h, gather1 -> m1h) -> safe.
    long long* bk = (long long*)m1h;

    hipMemsetAsync(bcnt, 0, NBKT * NSH * sizeof(int), stream);

    k_bscat<<<NTILE, 256, 0, stream>>>(ei, bcnt, bk);
    k_scan_bases<<<1, 256, 0, stream>>>(bcnt, bbase, row_ptr);
    k_csr<<<NBKT, 256, 0, stream>>>(bk, bcnt, bbase, row_ptr, csr);

    const int ntiles = (N_NODES + 63) / 64;
    k_gemm12<<<ntiles, 256, 0, stream>>>(x, Wl1, Wr1, y1h, z1h);
    k_gather1<<<(N_NODES + 3) / 4, 256, 0, stream>>>(row_ptr, csr, y1h, m1h);
    k_l2fin<<<ntiles, 256, 0, stream>>>(z1h, m1h, bl1, Wl2, Wr2, y2h, z2h);
    k_gather2_out<<<(N_NODES + 3) / 4, 256, 0, stream>>>(row_ptr, csr, y2h, z2h,
                                                         bl2, out);
}